// Round 1
// 617.243 us; speedup vs baseline: 1.1129x; 1.1129x over previous
//
#include <hip/hip_runtime.h>

#define C_   192
#define N_   32
#define H_   112
#define W_   112
#define W4   28                 // float4s per row
#define V_   4                  // output rows per thread
#define HT   (H_ / V_)          // 28 vertical tiles
#define P2   (HT * W4)          // 784 tiles per (n,c) plane
#define BLK  256
#define GX   ((P2 + BLK - 1) / BLK)   // 4

// Zero the per-channel sum/sumsq accumulators (ws is poisoned 0xAA each call).
__global__ void zero_acc_kernel(float* __restrict__ acc) {
    for (int i = threadIdx.x; i < 2 * C_; i += blockDim.x) acc[i] = 0.0f;
}

struct Row { float l; float4 m; float r; };

__device__ __forceinline__ Row load_row(const float* __restrict__ row, int j) {
    const float* p = row + 4 * j;
    Row r;
    r.m = *(const float4*)p;
    r.l = (j > 0)      ? p[-1] : 0.0f;
    r.r = (j < W4 - 1) ? p[4]  : 0.0f;
    return r;
}

__device__ __forceinline__ void fma_row(const Row& r, float w0, float w1, float w2,
                                        float4& a) {
    a.x += w0 * r.l   + w1 * r.m.x + w2 * r.m.y;
    a.y += w0 * r.m.x + w1 * r.m.y + w2 * r.m.z;
    a.z += w0 * r.m.y + w1 * r.m.z + w2 * r.m.w;
    a.w += w0 * r.m.z + w1 * r.m.w + w2 * r.r;
}

// 3x3 depthwise conv (bias cancels in BN), zero padding.
// Computes a V_ x 4 output tile; loads V_+2 rows once each.
__device__ __forceinline__ void conv_tile(const float* __restrict__ plane,
                                          int ht, int j, const float* wc,
                                          float4 y[V_]) {
    Row rows[V_ + 2];
    const float* rp = plane + (size_t)(ht * V_) * W_;
    if (ht > 0) rows[0] = load_row(rp - W_, j);
    else        rows[0] = Row{0.f, {0.f, 0.f, 0.f, 0.f}, 0.f};
#pragma unroll
    for (int v = 0; v < V_; ++v) rows[1 + v] = load_row(rp + v * W_, j);
    if (ht < HT - 1) rows[V_ + 1] = load_row(rp + (size_t)V_ * W_, j);
    else             rows[V_ + 1] = Row{0.f, {0.f, 0.f, 0.f, 0.f}, 0.f};

#pragma unroll
    for (int v = 0; v < V_; ++v) {
        float4 a = {0.f, 0.f, 0.f, 0.f};
        fma_row(rows[v],     wc[0], wc[1], wc[2], a);
        fma_row(rows[v + 1], wc[3], wc[4], wc[5], a);
        fma_row(rows[v + 2], wc[6], wc[7], wc[8], a);
        y[v] = a;
    }
}

// Pass 1: per-channel sum and sum-of-squares of the (biasless) conv output.
__global__ __launch_bounds__(BLK) void stats_kernel(const float* __restrict__ in,
                                                    const float* __restrict__ w,
                                                    float* __restrict__ acc) {
    const int nc = blockIdx.y;          // n*C + c
    const int c  = nc % C_;
    const int t  = blockIdx.x * BLK + threadIdx.x;

    float wc[9];
#pragma unroll
    for (int k = 0; k < 9; ++k) wc[k] = w[c * 9 + k];

    float s = 0.0f, ss = 0.0f;
    if (t < P2) {
        const int ht = t / W4, j = t % W4;
        const float* plane = in + (size_t)nc * (H_ * W_);
        float4 y[V_];
        conv_tile(plane, ht, j, wc, y);
#pragma unroll
        for (int v = 0; v < V_; ++v) {
            s  += (y[v].x + y[v].y) + (y[v].z + y[v].w);
            ss += (y[v].x * y[v].x + y[v].y * y[v].y)
                + (y[v].z * y[v].z + y[v].w * y[v].w);
        }
    }

    // wave-64 reduction
#pragma unroll
    for (int off = 32; off > 0; off >>= 1) {
        s  += __shfl_down(s,  off, 64);
        ss += __shfl_down(ss, off, 64);
    }
    __shared__ float ls[BLK / 64], lss[BLK / 64];
    const int lane = threadIdx.x & 63;
    const int wv   = threadIdx.x >> 6;
    if (lane == 0) { ls[wv] = s; lss[wv] = ss; }
    __syncthreads();
    if (threadIdx.x == 0) {
        float S  = 0.f, SS = 0.f;
#pragma unroll
        for (int i = 0; i < BLK / 64; ++i) { S += ls[i]; SS += lss[i]; }
        atomicAdd(&acc[c],      S);
        atomicAdd(&acc[C_ + c], SS);
    }
}

// Pass 1.5: fold stats + gamma/beta into per-channel scale/shift.
__global__ void finalize_kernel(const float* __restrict__ acc,
                                const float* __restrict__ gamma,
                                const float* __restrict__ beta,
                                float* __restrict__ st) {
    const int c = threadIdx.x;
    if (c < C_) {
        const float M    = (float)N_ * (float)H_ * (float)W_;
        const float mean = acc[c] / M;
        float var        = acc[C_ + c] / M - mean * mean;
        var              = fmaxf(var, 0.0f);
        const float sc   = gamma[c] * rsqrtf(var + 1e-5f);
        st[c]       = sc;
        st[C_ + c]  = beta[c] - sc * mean;   // conv bias b cancels algebraically
    }
}

// Pass 2: recompute conv, apply scale/shift + ReLU6, store V_ rows.
__global__ __launch_bounds__(BLK) void apply_kernel(const float* __restrict__ in,
                                                    const float* __restrict__ w,
                                                    const float* __restrict__ st,
                                                    float* __restrict__ out) {
    const int nc = blockIdx.y;
    const int c  = nc % C_;
    const int t  = blockIdx.x * BLK + threadIdx.x;
    if (t >= P2) return;

    float wc[9];
#pragma unroll
    for (int k = 0; k < 9; ++k) wc[k] = w[c * 9 + k];
    const float sc = st[c];
    const float sh = st[C_ + c];

    const int ht = t / W4, j = t % W4;
    const float* plane = in + (size_t)nc * (H_ * W_);
    float4 y[V_];
    conv_tile(plane, ht, j, wc, y);

    float* orow = out + (size_t)nc * (H_ * W_) + (size_t)(ht * V_) * W_ + 4 * j;
#pragma unroll
    for (int v = 0; v < V_; ++v) {
        float4 z;
        z.x = fminf(fmaxf(sc * y[v].x + sh, 0.0f), 6.0f);
        z.y = fminf(fmaxf(sc * y[v].y + sh, 0.0f), 6.0f);
        z.z = fminf(fmaxf(sc * y[v].z + sh, 0.0f), 6.0f);
        z.w = fminf(fmaxf(sc * y[v].w + sh, 0.0f), 6.0f);
        *(float4*)(orow + (size_t)v * W_) = z;
    }
}

extern "C" void kernel_launch(void* const* d_in, const int* in_sizes, int n_in,
                              void* d_out, int out_size, void* d_ws, size_t ws_size,
                              hipStream_t stream) {
    const float* in    = (const float*)d_in[0];
    const float* w     = (const float*)d_in[1];
    // d_in[2] = conv bias b: unused — cancels exactly inside training-mode BN.
    const float* gamma = (const float*)d_in[3];
    const float* beta  = (const float*)d_in[4];
    float* out = (float*)d_out;

    float* acc = (float*)d_ws;      // [0, 2C): sum, sumsq
    float* st  = acc + 2 * C_;      // [2C, 4C): scale, shift

    hipLaunchKernelGGL(zero_acc_kernel, dim3(1), dim3(64), 0, stream, acc);

    const dim3 grid(GX, N_ * C_);
    hipLaunchKernelGGL(stats_kernel, grid, dim3(BLK), 0, stream, in, w, acc);
    hipLaunchKernelGGL(finalize_kernel, dim3(1), dim3(C_), 0, stream,
                       acc, gamma, beta, st);
    hipLaunchKernelGGL(apply_kernel, grid, dim3(BLK), 0, stream, in, w, st, out);
}